// Round 3
// baseline (3780.357 us; speedup 1.0000x reference)
//
#include <hip/hip_runtime.h>
#include <cstdint>
#include <cstddef>

// ---------------- problem constants ----------------
#define DI 2048   // D_INNER
#define DM 1024   // DIM
#define BB 8      // batch
#define TT 1024   // seq len
#define ROWS (BB*TT)  // 8192
#define NSCAN 4   // scan blocks (2 batches each)

typedef short  short8 __attribute__((ext_vector_type(8)));
typedef float  f32x4  __attribute__((ext_vector_type(4)));

// ---------------- helpers ----------------
__device__ __forceinline__ unsigned short f2bf(float f) {
  unsigned int u = __builtin_bit_cast(unsigned int, f);
  u = u + 0x7fffu + ((u >> 16) & 1u);   // RNE
  return (unsigned short)(u >> 16);
}
__device__ __forceinline__ float fast_tanh(float x) {
  float ax = fabsf(x);
  float e  = __expf(-2.0f * ax);
  float t  = (1.0f - e) / (1.0f + e);
  return x < 0.0f ? -t : t;
}
__device__ __forceinline__ float silu_f(float z) {
  return z / (1.0f + __expf(-z));
}
__device__ __forceinline__ unsigned mulpk(unsigned a, unsigned b) {
  float a0 = __builtin_bit_cast(float, a << 16);
  float a1 = __builtin_bit_cast(float, a & 0xffff0000u);
  float b0 = __builtin_bit_cast(float, b << 16);
  float b1 = __builtin_bit_cast(float, b & 0xffff0000u);
  unsigned r0 = f2bf(a0 * b0), r1 = f2bf(a1 * b1);
  return r0 | (r1 << 16);
}
__device__ __forceinline__ uint4 pack8(const unsigned short* q) {
  uint4 p;
  p.x = (unsigned)q[0] | ((unsigned)q[1] << 16);
  p.y = (unsigned)q[2] | ((unsigned)q[3] << 16);
  p.z = (unsigned)q[4] | ((unsigned)q[5] << 16);
  p.w = (unsigned)q[6] | ((unsigned)q[7] << 16);
  return p;
}

// ---------------- f32 -> bf16 cast (4 elems/thread) ----------------
__global__ void cast_k(const float* __restrict__ s, short* __restrict__ d, int n4) {
  int i = blockIdx.x * 256 + threadIdx.x;
  if (i >= n4) return;
  float4 f = ((const float4*)s)[i];
  unsigned lo = (unsigned)f2bf(f.x) | ((unsigned)f2bf(f.y) << 16);
  unsigned hi = (unsigned)f2bf(f.z) | ((unsigned)f2bf(f.w) << 16);
  uint2 o; o.x = lo; o.y = hi;
  ((uint2*)d)[i] = o;
}

// ---------------- build circulant Bt for c_x: C[n][k] = c_x[(n-k) mod D] ----------------
__global__ void build_cx_k(const float* __restrict__ cx, short* __restrict__ C) {
  int tid = blockIdx.x * 256 + threadIdx.x;          // 0 .. 2048*256-1
  int n   = tid >> 8;
  int k0  = (tid & 255) * 8;
  unsigned short q[8];
#pragma unroll
  for (int j = 0; j < 8; ++j) q[j] = f2bf(cx[(n - (k0 + j)) & (DI - 1)]);
  *(uint4*)(C + (size_t)n * DI + k0) = pack8(q);
}

// ---------------- generic bf16 MFMA GEMM: C[M,N] = A[M,K] * Bt[N,K]^T ----------------
// A2 (optional): elementwise bf16 multiplier on A (fused cell = h*gate).
// mode 0: bf16 out; 1: f32 out + bias; 2: bf16 out + bias + silu; 3: f32 out
__global__ __launch_bounds__(256) void gemm_k(
    const short* __restrict__ A, const short* __restrict__ A2,
    const short* __restrict__ Bt,
    int M, int N, int K, int mode, const float* __restrict__ bias,
    float* __restrict__ outF, short* __restrict__ outH)
{
  __shared__ __align__(16) short As[128 * 40];
  __shared__ __align__(16) short Bs[128 * 40];
  const int tid  = threadIdx.x;
  const int m0   = blockIdx.y * 128, n0 = blockIdx.x * 128;
  const int wave = tid >> 6, lane = tid & 63;
  const int wy = wave >> 1, wx = wave & 1;
  const int l = lane & 15, G = lane >> 4;
  const int srow = tid >> 1, sseg = tid & 1;

  f32x4 acc[4][4];
#pragma unroll
  for (int i = 0; i < 4; ++i)
#pragma unroll
    for (int j = 0; j < 4; ++j) acc[i][j] = (f32x4){0.f, 0.f, 0.f, 0.f};

  for (int k0 = 0; k0 < K; k0 += 32) {
    if (k0) __syncthreads();
    const short* ga = A  + (size_t)(m0 + srow) * K + k0 + sseg * 16;
    const short* gb = Bt + (size_t)(n0 + srow) * K + k0 + sseg * 16;
    uint4 a0 = *(const uint4*)ga;
    uint4 a1 = *(const uint4*)(ga + 8);
    if (A2) {
      const short* g2 = A2 + (size_t)(m0 + srow) * K + k0 + sseg * 16;
      uint4 m0v = *(const uint4*)g2;
      uint4 m1v = *(const uint4*)(g2 + 8);
      a0.x = mulpk(a0.x, m0v.x); a0.y = mulpk(a0.y, m0v.y);
      a0.z = mulpk(a0.z, m0v.z); a0.w = mulpk(a0.w, m0v.w);
      a1.x = mulpk(a1.x, m1v.x); a1.y = mulpk(a1.y, m1v.y);
      a1.z = mulpk(a1.z, m1v.z); a1.w = mulpk(a1.w, m1v.w);
    }
    uint4 b0 = *(const uint4*)gb;
    uint4 b1 = *(const uint4*)(gb + 8);
    *(uint4*)&As[srow * 40 + sseg * 16]     = a0;
    *(uint4*)&As[srow * 40 + sseg * 16 + 8] = a1;
    *(uint4*)&Bs[srow * 40 + sseg * 16]     = b0;
    *(uint4*)&Bs[srow * 40 + sseg * 16 + 8] = b1;
    __syncthreads();
    short8 af[4], bfv[4];
#pragma unroll
    for (int i = 0; i < 4; ++i) af[i]  = *(const short8*)&As[(64 * wy + 16 * i + l) * 40 + 8 * G];
#pragma unroll
    for (int j = 0; j < 4; ++j) bfv[j] = *(const short8*)&Bs[(64 * wx + 16 * j + l) * 40 + 8 * G];
#pragma unroll
    for (int i = 0; i < 4; ++i)
#pragma unroll
      for (int j = 0; j < 4; ++j)
        acc[i][j] = __builtin_amdgcn_mfma_f32_16x16x32_bf16(af[i], bfv[j], acc[i][j], 0, 0, 0);
  }

#pragma unroll
  for (int j = 0; j < 4; ++j) {
    const int c = n0 + 64 * wx + 16 * j + l;
    float bv = 0.f;
    if (mode == 1 || mode == 2) bv = bias[c];
#pragma unroll
    for (int i = 0; i < 4; ++i) {
      const int r0 = m0 + 64 * wy + 16 * i + 4 * G;
#pragma unroll
      for (int v = 0; v < 4; ++v) {
        float z = acc[i][j][v] + bv;
        size_t off = (size_t)(r0 + v) * N + c;
        if (mode == 0)      outH[off] = (short)f2bf(z);
        else if (mode == 2) outH[off] = (short)f2bf(silu_f(z));
        else                outF[off] = z;
      }
    }
  }
}

// ---------------- fused: scan (blocks 0..3, 2 batches each) + gate GEMM ----------------
// Scan step is latency/overhead-bound, not LDS-bound (R2 evidence). Amortize:
// each block runs TWO independent batch recurrences; every barrier-to-barrier
// phase holds 2 matvecs + 2 epilogues, so barriers/drains/latency chains are
// paid once per TWO steps, and 2x independent work hides the chains.
//   matvec (per batch): n = 16mt + r + 128q; 8 waves = 8-way K-split (256);
//   A-frags static (22 diagonal classes, shared by both batches);
//   B-frags from XOR-swizzled h_lds (1 read feeds 8 MFMAs).
// hseq store issued at the TOP of the next phase (drain overlaps MFMA phase).
__global__ __launch_bounds__(512, 2) void fused_k(
    const float* __restrict__ pre, const float* __restrict__ h0,
    const float* __restrict__ ch, short* __restrict__ hseq,
    float* __restrict__ hfin,
    const short* __restrict__ xproj, const short* __restrict__ wg,
    const float* __restrict__ bg, short* __restrict__ gate)
{
  __shared__ __align__(16) char smem[139264];  // scan: 2x4K h + 2x64K partials
  const int bid = blockIdx.x;
  const int tid = threadIdx.x;

  if (bid < NSCAN) {
    // ================= scan path (2 batches per block) =================
    float* part = (float*)(smem + 8192);     // [2][8][2048] f32, swizzled
    const int kg   = tid >> 6;               // wave id = K-slice [256*kg, ...)
    const int lane = tid & 63;
    const int q    = lane & 15;              // MFMA col (B) / row (A)
    const int G    = lane >> 4;              // k-subgroup in [0,4)

    // A fragments: 22 diagonal classes, w = mt - 2s in [-14,7], idx = w+14.
    short8 av[22];
#pragma unroll
    for (int idx = 0; idx < 22; ++idx) {
      const int base = 16 * (idx - 14) + q - 8 * G - 256 * kg;
      short8 v;
#pragma unroll
      for (int j = 0; j < 8; ++j)
        v[j] = (short)f2bf(ch[(base - j) & (DI - 1)]);
      av[idx] = v;
    }

    // init h_lds (swizzled) + pcur for both batches
    float4 pcur[2];
#pragma unroll
    for (int bt = 0; bt < 2; ++bt) {
      short* h_lds = (short*)(smem + bt * 4096);
      const int b = 2 * bid + bt;
      float4 hv = *(const float4*)(h0 + b * DI + 4 * tid);
      unsigned lo = (unsigned)f2bf(hv.x) | ((unsigned)f2bf(hv.y) << 16);
      unsigned hi = (unsigned)f2bf(hv.z) | ((unsigned)f2bf(hv.w) << 16);
      const int blk = tid >> 1;
      const int pb  = blk ^ ((blk >> 4) & 7);
      uint2 w; w.x = lo; w.y = hi;
      *(uint2*)&h_lds[pb * 8 + 4 * (tid & 1)] = w;
      pcur[bt] = *(const float4*)(pre + (size_t)b * TT * DI + 4 * tid);
    }
    __syncthreads();

    const int rbase = 32 * kg + G + 16 * q;  // B-frag block base (s=0)
    uint2 wprev[2];
    wprev[0] = (uint2){0u, 0u}; wprev[1] = (uint2){0u, 0u};

    for (int t = 0; t < TT; ++t) {
      // prefetch next pre rows (consumed next iteration; drains at barrier A)
      float4 pf[2];
#pragma unroll
      for (int bt = 0; bt < 2; ++bt) {
        const float* pn = pre + (size_t)(2 * bid + bt) * TT * DI
                        + (size_t)(t + 1 < TT ? t + 1 : t) * DI;
        pf[bt] = *(const float4*)(pn + 4 * tid);
      }
      // store previous step's h rows (drain overlaps this phase's MFMAs)
      if (t) {
#pragma unroll
        for (int bt = 0; bt < 2; ++bt)
          *(uint2*)(hseq + (size_t)((2 * bid + bt) * TT + t - 1) * DI + 4 * tid) = wprev[bt];
      }

      // ---- two independent matvecs ----
#pragma unroll
      for (int bt = 0; bt < 2; ++bt) {
        const short* h_lds = (const short*)(smem + bt * 4096);
        f32x4 acc[8];
#pragma unroll
        for (int mt = 0; mt < 8; ++mt) acc[mt] = (f32x4){0.f, 0.f, 0.f, 0.f};
#pragma unroll
        for (int s = 0; s < 8; ++s) {
          const int blk = (rbase + 4 * s) & 255;
          const int pb  = blk ^ ((blk >> 4) & 7);
          short8 bv = *(const short8*)&h_lds[pb * 8];
#pragma unroll
          for (int mt = 0; mt < 8; ++mt)
            acc[mt] = __builtin_amdgcn_mfma_f32_16x16x32_bf16(av[mt - 2 * s + 14], bv, acc[mt], 0, 0, 0);
        }
        float* pk = part + bt * 16384 + (kg << 11);
#pragma unroll
        for (int mt = 0; mt < 8; ++mt) {
          const int nb  = 4 * mt + G + 32 * q;
          const int pnb = nb ^ ((nb >> 5) & 7);
          *(f32x4*)&pk[4 * pnb] = acc[mt];
        }
      }
      __syncthreads();   // barrier A: partials (both batches) visible

      // ---- two epilogues ----
#pragma unroll
      for (int bt = 0; bt < 2; ++bt) {
        const int pnb = tid ^ ((tid >> 5) & 7);
        const float* pp = part + bt * 16384 + 4 * pnb;
        float4 c0 = *(const float4*)(pp);
        float4 c1 = *(const float4*)(pp + 2048);
        float4 c2 = *(const float4*)(pp + 4096);
        float4 c3 = *(const float4*)(pp + 6144);
        float4 c4 = *(const float4*)(pp + 8192);
        float4 c5 = *(const float4*)(pp + 10240);
        float4 c6 = *(const float4*)(pp + 12288);
        float4 c7 = *(const float4*)(pp + 14336);
        float z0 = ((c0.x + c1.x) + (c2.x + c3.x)) + ((c4.x + c5.x) + (c6.x + c7.x)) + pcur[bt].x;
        float z1 = ((c0.y + c1.y) + (c2.y + c3.y)) + ((c4.y + c5.y) + (c6.y + c7.y)) + pcur[bt].y;
        float z2 = ((c0.z + c1.z) + (c2.z + c3.z)) + ((c4.z + c5.z) + (c6.z + c7.z)) + pcur[bt].z;
        float z3 = ((c0.w + c1.w) + (c2.w + c3.w)) + ((c4.w + c5.w) + (c6.w + c7.w)) + pcur[bt].w;
        float t0 = fast_tanh(z0), t1 = fast_tanh(z1);
        float t2 = fast_tanh(z2), t3 = fast_tanh(z3);
        unsigned lo = (unsigned)f2bf(t0) | ((unsigned)f2bf(t1) << 16);
        unsigned hi = (unsigned)f2bf(t2) | ((unsigned)f2bf(t3) << 16);
        const int blk = tid >> 1;
        const int pb  = blk ^ ((blk >> 4) & 7);
        uint2 w; w.x = lo; w.y = hi;
        short* h_lds = (short*)(smem + bt * 4096);
        *(uint2*)&h_lds[pb * 8 + 4 * (tid & 1)] = w;
        wprev[bt] = w;
        if (t == TT - 1) {
          float4 hf; hf.x = t0; hf.y = t1; hf.z = t2; hf.w = t3;
          *(float4*)(hfin + (2 * bid + bt) * DI + 4 * tid) = hf;
        }
      }
      __syncthreads();   // barrier B: h_t complete before next step's B reads
      pcur[0] = pf[0]; pcur[1] = pf[1];
    }
    // final hseq rows
#pragma unroll
    for (int bt = 0; bt < 2; ++bt)
      *(uint2*)(hseq + (size_t)((2 * bid + bt) * TT + TT - 1) * DI + 4 * tid) = wprev[bt];
  } else {
    // ================= gate GEMM path (persistent tiles) =================
    // tile = 256 rows x 128 cols; 8 waves: wy in [0,4), wx in [0,2)
    short* As = (short*)smem;              // 256 x 40
    short* Bs = (short*)(smem + 20480);    // 128 x 40
    const int wid = tid >> 6, lane = tid & 63;
    const int wy = wid >> 1, wx = wid & 1;
    const int l = lane & 15, G = lane >> 4;

    for (int tile = bid - NSCAN; tile < 512; tile += (256 - NSCAN)) {
      const int m0 = (tile & 31) * 256, n0 = (tile >> 5) * 128;
      f32x4 acc[4][4];
#pragma unroll
      for (int i = 0; i < 4; ++i)
#pragma unroll
        for (int j = 0; j < 4; ++j) acc[i][j] = (f32x4){0.f, 0.f, 0.f, 0.f};

      for (int k0 = 0; k0 < DI; k0 += 32) {
        __syncthreads();
        const short* ga = xproj + (size_t)(m0 + (tid >> 1)) * DI + k0 + (tid & 1) * 16;
        const short* gb = wg    + (size_t)(n0 + (tid >> 2)) * DI + k0 + (tid & 3) * 8;
        uint4 a0 = *(const uint4*)ga;
        uint4 a1 = *(const uint4*)(ga + 8);
        uint4 b0 = *(const uint4*)gb;
        *(uint4*)&As[(tid >> 1) * 40 + (tid & 1) * 16]     = a0;
        *(uint4*)&As[(tid >> 1) * 40 + (tid & 1) * 16 + 8] = a1;
        *(uint4*)&Bs[(tid >> 2) * 40 + (tid & 3) * 8]      = b0;
        __syncthreads();
        short8 af[4], bfv[4];
#pragma unroll
        for (int i = 0; i < 4; ++i) af[i]  = *(const short8*)&As[(64 * wy + 16 * i + l) * 40 + 8 * G];
#pragma unroll
        for (int j = 0; j < 4; ++j) bfv[j] = *(const short8*)&Bs[(64 * wx + 16 * j + l) * 40 + 8 * G];
#pragma unroll
        for (int i = 0; i < 4; ++i)
#pragma unroll
          for (int j = 0; j < 4; ++j)
            acc[i][j] = __builtin_amdgcn_mfma_f32_16x16x32_bf16(af[i], bfv[j], acc[i][j], 0, 0, 0);
      }
#pragma unroll
      for (int j = 0; j < 4; ++j) {
        const int c = n0 + 64 * wx + 16 * j + l;
        const float bv = bg[c];
#pragma unroll
        for (int i = 0; i < 4; ++i) {
          const int r0 = m0 + 64 * wy + 16 * i + 4 * G;
#pragma unroll
          for (int v = 0; v < 4; ++v) {
            float z = acc[i][j][v] + bv;
            gate[(size_t)(r0 + v) * DI + c] = (short)f2bf(silu_f(z));
          }
        }
      }
      __syncthreads();   // protect LDS before next tile's staging
    }
  }
}

// ---------------- launch ----------------
extern "C" void kernel_launch(void* const* d_in, const int* in_sizes, int n_in,
                              void* d_out, int out_size, void* d_ws, size_t ws_size,
                              hipStream_t stream) {
  const float* x    = (const float*)d_in[0];   // [8,1024,1024]
  const float* h0   = (const float*)d_in[1];   // [8,2048]
  const float* win  = (const float*)d_in[2];   // [2048,1024]
  const float* wout = (const float*)d_in[3];   // [1024,2048]
  const float* ch   = (const float*)d_in[4];   // [2048]
  const float* cx   = (const float*)d_in[5];   // [2048]
  const float* bb   = (const float*)d_in[6];   // [2048]
  const float* wg   = (const float*)d_in[7];   // [2048,2048]
  const float* bg   = (const float*)d_in[8];   // [2048]
  float* out = (float*)d_out;                  // 8192*1024 output + 8*2048 h_final

  char* ws = (char*)d_ws;
  // liveness-packed workspace (peak 176,160,768 B)
  short* o_xb    = (short*)(ws + 0);           // 16.78M, dead after xproj gemm
  short* o_win   = (short*)(ws + 16777216);    // 4.19M,  dead after xproj gemm
  short* o_cx    = (short*)(ws + 20971520);    // 8.39M,  dead after pre gemm
  short* o_hseq  = (short*)(ws + 0);           // 33.55M, written by fused (above all dead)
  short* o_xproj = (short*)(ws + 33554432);    // 33.55M
  float* o_pre   = (float*)(ws + 67108864);    // 67.11M f32, dead after fused
  short* o_wout  = (short*)(ws + 67108864);    // 4.19M, cast AFTER fused (reuses pre)
  short* o_gate  = (short*)(ws + 134217728);   // 33.55M
  short* o_wg    = (short*)(ws + 167772160);   // 8.39M

  // 1) dtype conversions / circulant build
  cast_k<<<8192, 256, 0, stream>>>(x,   o_xb,  (BB * TT * DM) / 4);
  cast_k<<<2048, 256, 0, stream>>>(win, o_win, (DI * DM) / 4);
  cast_k<<<4096, 256, 0, stream>>>(wg,  o_wg,  (DI * DI) / 4);
  build_cx_k<<<2048, 256, 0, stream>>>(cx, o_cx);

  // 2) x_proj = x @ in_proj_w^T   [8192,2048] bf16
  gemm_k<<<dim3(DI / 128, ROWS / 128), 256, 0, stream>>>(
      o_xb, nullptr, o_win, ROWS, DI, DM, 0, nullptr, nullptr, o_xproj);

  // 3) pre = circ(c_x) x_proj + b   [8192,2048] f32
  gemm_k<<<dim3(DI / 128, ROWS / 128), 256, 0, stream>>>(
      o_xproj, nullptr, o_cx, ROWS, DI, DI, 1, bb, o_pre, nullptr);

  // 4) fused: scan (4 blocks x 2 batches) + gate GEMM (252 persistent blocks)
  fused_k<<<256, 512, 0, stream>>>(o_pre, h0, ch, o_hseq,
                                   out + (size_t)BB * TT * DM,
                                   o_xproj, o_wg, bg, o_gate);

  // 5) wout cast (into dead pre region)
  cast_k<<<2048, 256, 0, stream>>>(wout, o_wout, (DM * DI) / 4);

  // 6) output = (h_seq * gate) @ out_proj_w^T  — multiply fused into A-staging
  gemm_k<<<dim3(DM / 128, ROWS / 128), 256, 0, stream>>>(
      o_hseq, o_gate, o_wout, ROWS, DM, DI, 3, nullptr, out, nullptr);
}

// Round 4
// 2277.680 us; speedup vs baseline: 1.6597x; 1.6597x over previous
//
#include <hip/hip_runtime.h>
#include <cstdint>
#include <cstddef>

// ---------------- problem constants ----------------
#define DI 2048   // D_INNER
#define DM 1024   // DIM
#define BB 8      // batch
#define TT 1024   // seq len
#define ROWS (BB*TT)  // 8192
#define NSCAN 8   // scan blocks (1 batch each)

typedef short  short8 __attribute__((ext_vector_type(8)));
typedef float  f32x4  __attribute__((ext_vector_type(4)));
typedef float  f32x16 __attribute__((ext_vector_type(16)));

// ---------------- helpers ----------------
__device__ __forceinline__ unsigned short f2bf(float f) {
  unsigned int u = __builtin_bit_cast(unsigned int, f);
  u = u + 0x7fffu + ((u >> 16) & 1u);   // RNE
  return (unsigned short)(u >> 16);
}
__device__ __forceinline__ float fast_tanh(float x) {
  float ax = fabsf(x);
  float e  = __expf(-2.0f * ax);
  float t  = (1.0f - e) / (1.0f + e);
  return x < 0.0f ? -t : t;
}
__device__ __forceinline__ float silu_f(float z) {
  return z / (1.0f + __expf(-z));
}
__device__ __forceinline__ unsigned mulpk(unsigned a, unsigned b) {
  float a0 = __builtin_bit_cast(float, a << 16);
  float a1 = __builtin_bit_cast(float, a & 0xffff0000u);
  float b0 = __builtin_bit_cast(float, b << 16);
  float b1 = __builtin_bit_cast(float, b & 0xffff0000u);
  unsigned r0 = f2bf(a0 * b0), r1 = f2bf(a1 * b1);
  return r0 | (r1 << 16);
}
__device__ __forceinline__ uint4 pack8(const unsigned short* q) {
  uint4 p;
  p.x = (unsigned)q[0] | ((unsigned)q[1] << 16);
  p.y = (unsigned)q[2] | ((unsigned)q[3] << 16);
  p.z = (unsigned)q[4] | ((unsigned)q[5] << 16);
  p.w = (unsigned)q[6] | ((unsigned)q[7] << 16);
  return p;
}

// ---------------- f32 -> bf16 cast (4 elems/thread) ----------------
__global__ void cast_k(const float* __restrict__ s, short* __restrict__ d, int n4) {
  int i = blockIdx.x * 256 + threadIdx.x;
  if (i >= n4) return;
  float4 f = ((const float4*)s)[i];
  unsigned lo = (unsigned)f2bf(f.x) | ((unsigned)f2bf(f.y) << 16);
  unsigned hi = (unsigned)f2bf(f.z) | ((unsigned)f2bf(f.w) << 16);
  uint2 o; o.x = lo; o.y = hi;
  ((uint2*)d)[i] = o;
}

// ---------------- build circulant Bt for c_x: C[n][k] = c_x[(n-k) mod D] ----------------
__global__ void build_cx_k(const float* __restrict__ cx, short* __restrict__ C) {
  int tid = blockIdx.x * 256 + threadIdx.x;          // 0 .. 2048*256-1
  int n   = tid >> 8;
  int k0  = (tid & 255) * 8;
  unsigned short q[8];
#pragma unroll
  for (int j = 0; j < 8; ++j) q[j] = f2bf(cx[(n - (k0 + j)) & (DI - 1)]);
  *(uint4*)(C + (size_t)n * DI + k0) = pack8(q);
}

// ---------------- generic bf16 MFMA GEMM: C[M,N] = A[M,K] * Bt[N,K]^T ----------------
// A2 (optional): elementwise bf16 multiplier on A (fused cell = h*gate).
// mode 0: bf16 out; 1: f32 out + bias; 2: bf16 out + bias + silu; 3: f32 out
__global__ __launch_bounds__(256) void gemm_k(
    const short* __restrict__ A, const short* __restrict__ A2,
    const short* __restrict__ Bt,
    int M, int N, int K, int mode, const float* __restrict__ bias,
    float* __restrict__ outF, short* __restrict__ outH)
{
  __shared__ __align__(16) short As[128 * 40];
  __shared__ __align__(16) short Bs[128 * 40];
  const int tid  = threadIdx.x;
  const int m0   = blockIdx.y * 128, n0 = blockIdx.x * 128;
  const int wave = tid >> 6, lane = tid & 63;
  const int wy = wave >> 1, wx = wave & 1;
  const int l = lane & 15, G = lane >> 4;
  const int srow = tid >> 1, sseg = tid & 1;

  f32x4 acc[4][4];
#pragma unroll
  for (int i = 0; i < 4; ++i)
#pragma unroll
    for (int j = 0; j < 4; ++j) acc[i][j] = (f32x4){0.f, 0.f, 0.f, 0.f};

  for (int k0 = 0; k0 < K; k0 += 32) {
    if (k0) __syncthreads();
    const short* ga = A  + (size_t)(m0 + srow) * K + k0 + sseg * 16;
    const short* gb = Bt + (size_t)(n0 + srow) * K + k0 + sseg * 16;
    uint4 a0 = *(const uint4*)ga;
    uint4 a1 = *(const uint4*)(ga + 8);
    if (A2) {
      const short* g2 = A2 + (size_t)(m0 + srow) * K + k0 + sseg * 16;
      uint4 m0v = *(const uint4*)g2;
      uint4 m1v = *(const uint4*)(g2 + 8);
      a0.x = mulpk(a0.x, m0v.x); a0.y = mulpk(a0.y, m0v.y);
      a0.z = mulpk(a0.z, m0v.z); a0.w = mulpk(a0.w, m0v.w);
      a1.x = mulpk(a1.x, m1v.x); a1.y = mulpk(a1.y, m1v.y);
      a1.z = mulpk(a1.z, m1v.z); a1.w = mulpk(a1.w, m1v.w);
    }
    uint4 b0 = *(const uint4*)gb;
    uint4 b1 = *(const uint4*)(gb + 8);
    *(uint4*)&As[srow * 40 + sseg * 16]     = a0;
    *(uint4*)&As[srow * 40 + sseg * 16 + 8] = a1;
    *(uint4*)&Bs[srow * 40 + sseg * 16]     = b0;
    *(uint4*)&Bs[srow * 40 + sseg * 16 + 8] = b1;
    __syncthreads();
    short8 af[4], bfv[4];
#pragma unroll
    for (int i = 0; i < 4; ++i) af[i]  = *(const short8*)&As[(64 * wy + 16 * i + l) * 40 + 8 * G];
#pragma unroll
    for (int j = 0; j < 4; ++j) bfv[j] = *(const short8*)&Bs[(64 * wx + 16 * j + l) * 40 + 8 * G];
#pragma unroll
    for (int i = 0; i < 4; ++i)
#pragma unroll
      for (int j = 0; j < 4; ++j)
        acc[i][j] = __builtin_amdgcn_mfma_f32_16x16x32_bf16(af[i], bfv[j], acc[i][j], 0, 0, 0);
  }

#pragma unroll
  for (int j = 0; j < 4; ++j) {
    const int c = n0 + 64 * wx + 16 * j + l;
    float bv = 0.f;
    if (mode == 1 || mode == 2) bv = bias[c];
#pragma unroll
    for (int i = 0; i < 4; ++i) {
      const int r0 = m0 + 64 * wy + 16 * i + 4 * G;
#pragma unroll
      for (int v = 0; v < 4; ++v) {
        float z = acc[i][j][v] + bv;
        size_t off = (size_t)(r0 + v) * N + c;
        if (mode == 0)      outH[off] = (short)f2bf(z);
        else if (mode == 2) outH[off] = (short)f2bf(silu_f(z));
        else                outF[off] = z;
      }
    }
  }
}

// ---------------- fused: scan (blocks 0..7) + gate GEMM (blocks 8..255) ----------------
// Scan pipe accounting (R2/R3 evidence): matrix pipe is the wall.
//   -> 32x32x16 MFMA (4061 FLOP/cy vs 3377): 512->256 MFMAs, 2064 cy floor.
//   n = 32mt + r + 64q, mt in [0,2), r in [0,32), q in [0,32)
//   A[u][k] = c_h[(u-k) mod D], u = 32mt+r (circulant: 34 diagonal classes in regs)
//   B[k][q] = h[(k+64q) mod D]  (XOR-swizzled LDS; 1 read feeds both mt tiles)
//   -> 4 compute waves (K=512 each): partial buffers 8->4, serial epilogue
//      LDS reads halve. Waves 4-7: prefetch/store/epilogue only.
// hseq stored from regs at phase top; pre prefetched 1-ahead into regs. Drains
// hide under the ~2.2k-cy compute phase.
__global__ __launch_bounds__(512, 2) void fused_k(
    const float* __restrict__ pre, const float* __restrict__ h0,
    const float* __restrict__ ch, short* __restrict__ hseq,
    float* __restrict__ hfin,
    const short* __restrict__ xproj, const short* __restrict__ wg,
    const float* __restrict__ bg, short* __restrict__ gate)
{
  __shared__ __align__(16) char smem[81920];   // padded to force 1 block/CU
  const int bid = blockIdx.x;
  const int tid = threadIdx.x;

  if (bid < NSCAN) {
    // ================= scan path (1 batch per block) =================
    short* h_lds = (short*)smem;             // 2048 bf16, swizzled 8-elem blocks
    float* part  = (float*)(smem + 4096);    // 4 x 2048 f32, swizzled f32x4 blocks
    const int b    = bid;
    const int wid  = tid >> 6;
    const int lane = tid & 63;
    const int kg   = wid;                    // compute waves: K-slice [512kg, ...)
    const int qc   = lane & 31;              // MFMA col (B) / row (A)
    const int Gc   = lane >> 5;              // k-subgroup in [0,2)
    const float* preB = pre + (size_t)b * TT * DI;

    // A fragments: 34 diagonal classes, w = 2mt - s in [-31,2], idx = w+31.
    // element (lane, j) = c_h[(16w + (lane&31) - 8*(lane>>5) - 512kg - j) mod D]
    short8 av[34];
    if (wid < 4) {
#pragma unroll
      for (int idx = 0; idx < 34; ++idx) {
        const int base = 16 * (idx - 31) + qc - 8 * Gc - 512 * kg;
        short8 v;
#pragma unroll
        for (int j = 0; j < 8; ++j)
          v[j] = (short)f2bf(ch[(base - j) & (DI - 1)]);
        av[idx] = v;
      }
    }

    // init h_lds (swizzled): thread writes elems n = 4*tid .. 4*tid+3
    {
      float4 hv = *(const float4*)(h0 + b * DI + 4 * tid);
      unsigned lo = (unsigned)f2bf(hv.x) | ((unsigned)f2bf(hv.y) << 16);
      unsigned hi = (unsigned)f2bf(hv.z) | ((unsigned)f2bf(hv.w) << 16);
      const int blk = tid >> 1;
      const int pb  = blk ^ ((blk >> 4) & 7);
      uint2 w; w.x = lo; w.y = hi;
      *(uint2*)&h_lds[pb * 8 + 4 * (tid & 1)] = w;
    }
    float4 pcur = *(const float4*)(preB + 4 * tid);   // pre_0 in registers
    __syncthreads();

    uint2 wprev; wprev.x = 0u; wprev.y = 0u;

    for (int t = 0; t < TT; ++t) {
      // prefetch next pre row (consumed next iter; drains under compute phase)
      const float* pn = preB + (size_t)(t + 1 < TT ? t + 1 : t) * DI;
      float4 pf = *(const float4*)(pn + 4 * tid);
      // store previous step's h row (drain overlaps this phase's MFMAs)
      if (t)
        *(uint2*)(hseq + (size_t)(b * TT + t - 1) * DI + 4 * tid) = wprev;

      if (wid < 4) {
        // ---- matvec: 2 x 32x32x16 acc chains, 32 K-chunks of 16 ----
        f32x16 acc0, acc1;
#pragma unroll
        for (int v = 0; v < 16; ++v) { acc0[v] = 0.f; acc1[v] = 0.f; }
#pragma unroll
        for (int s = 0; s < 32; ++s) {
          const int blk = (64 * kg + 2 * s + Gc + 8 * qc) & 255;
          const int pb  = blk ^ ((blk >> 4) & 7);
          short8 bv = *(const short8*)&h_lds[pb * 8];
          acc0 = __builtin_amdgcn_mfma_f32_32x32x16_bf16(av[31 - s], bv, acc0, 0, 0, 0);
          acc1 = __builtin_amdgcn_mfma_f32_32x32x16_bf16(av[33 - s], bv, acc1, 0, 0, 0);
        }
        // partial write: n = 32mt + (reg&3) + 8*(reg>>2) + 4Gc + 64qc
        float* pk = part + (kg << 11);
#pragma unroll
        for (int s4 = 0; s4 < 4; ++s4) {
          {
            const int nb  = 2 * s4 + Gc + 16 * qc;           // mt = 0
            const int pnb = nb ^ ((nb >> 4) & 7);
            float4 w;
            w.x = acc0[4 * s4 + 0]; w.y = acc0[4 * s4 + 1];
            w.z = acc0[4 * s4 + 2]; w.w = acc0[4 * s4 + 3];
            *(float4*)&pk[4 * pnb] = w;
          }
          {
            const int nb  = 8 + 2 * s4 + Gc + 16 * qc;       // mt = 1
            const int pnb = nb ^ ((nb >> 4) & 7);
            float4 w;
            w.x = acc1[4 * s4 + 0]; w.y = acc1[4 * s4 + 1];
            w.z = acc1[4 * s4 + 2]; w.w = acc1[4 * s4 + 3];
            *(float4*)&pk[4 * pnb] = w;
          }
        }
      }
      __syncthreads();   // barrier A: partials visible

      // epilogue (all 512 threads): reduce 4 partials, add pre, tanh, write h
      {
        const int pe = tid ^ ((tid >> 4) & 7);
        const float* pp = part + 4 * pe;
        float4 c0 = *(const float4*)(pp);
        float4 c1 = *(const float4*)(pp + 2048);
        float4 c2 = *(const float4*)(pp + 4096);
        float4 c3 = *(const float4*)(pp + 6144);
        float z0 = (c0.x + c1.x) + (c2.x + c3.x) + pcur.x;
        float z1 = (c0.y + c1.y) + (c2.y + c3.y) + pcur.y;
        float z2 = (c0.z + c1.z) + (c2.z + c3.z) + pcur.z;
        float z3 = (c0.w + c1.w) + (c2.w + c3.w) + pcur.w;
        float t0 = fast_tanh(z0), t1 = fast_tanh(z1);
        float t2 = fast_tanh(z2), t3 = fast_tanh(z3);
        unsigned lo = (unsigned)f2bf(t0) | ((unsigned)f2bf(t1) << 16);
        unsigned hi = (unsigned)f2bf(t2) | ((unsigned)f2bf(t3) << 16);
        const int blk = tid >> 1;
        const int pb  = blk ^ ((blk >> 4) & 7);
        uint2 w; w.x = lo; w.y = hi;
        *(uint2*)&h_lds[pb * 8 + 4 * (tid & 1)] = w;
        wprev = w;
        if (t == TT - 1) {
          float4 hf; hf.x = t0; hf.y = t1; hf.z = t2; hf.w = t3;
          *(float4*)(hfin + b * DI + 4 * tid) = hf;
        }
      }
      __syncthreads();   // barrier B: h_t complete before next step's B reads
      pcur = pf;
    }
    // final hseq row
    *(uint2*)(hseq + (size_t)(b * TT + TT - 1) * DI + 4 * tid) = wprev;
  } else {
    // ================= gate GEMM path (persistent tiles) =================
    // tile = 256 rows x 128 cols; 8 waves: wy in [0,4), wx in [0,2)
    short* As = (short*)smem;              // 256 x 40
    short* Bs = (short*)(smem + 20480);    // 128 x 40
    const int wid = tid >> 6, lane = tid & 63;
    const int wy = wid >> 1, wx = wid & 1;
    const int l = lane & 15, G = lane >> 4;

    for (int tile = bid - NSCAN; tile < 512; tile += (256 - NSCAN)) {
      const int m0 = (tile & 31) * 256, n0 = (tile >> 5) * 128;
      f32x4 acc[4][4];
#pragma unroll
      for (int i = 0; i < 4; ++i)
#pragma unroll
        for (int j = 0; j < 4; ++j) acc[i][j] = (f32x4){0.f, 0.f, 0.f, 0.f};

      for (int k0 = 0; k0 < DI; k0 += 32) {
        __syncthreads();
        const short* ga = xproj + (size_t)(m0 + (tid >> 1)) * DI + k0 + (tid & 1) * 16;
        const short* gb = wg    + (size_t)(n0 + (tid >> 2)) * DI + k0 + (tid & 3) * 8;
        uint4 a0 = *(const uint4*)ga;
        uint4 a1 = *(const uint4*)(ga + 8);
        uint4 b0 = *(const uint4*)gb;
        *(uint4*)&As[(tid >> 1) * 40 + (tid & 1) * 16]     = a0;
        *(uint4*)&As[(tid >> 1) * 40 + (tid & 1) * 16 + 8] = a1;
        *(uint4*)&Bs[(tid >> 2) * 40 + (tid & 3) * 8]      = b0;
        __syncthreads();
        short8 af[4], bfv[4];
#pragma unroll
        for (int i = 0; i < 4; ++i) af[i]  = *(const short8*)&As[(64 * wy + 16 * i + l) * 40 + 8 * G];
#pragma unroll
        for (int j = 0; j < 4; ++j) bfv[j] = *(const short8*)&Bs[(64 * wx + 16 * j + l) * 40 + 8 * G];
#pragma unroll
        for (int i = 0; i < 4; ++i)
#pragma unroll
          for (int j = 0; j < 4; ++j)
            acc[i][j] = __builtin_amdgcn_mfma_f32_16x16x32_bf16(af[i], bfv[j], acc[i][j], 0, 0, 0);
      }
#pragma unroll
      for (int j = 0; j < 4; ++j) {
        const int c = n0 + 64 * wx + 16 * j + l;
        const float bv = bg[c];
#pragma unroll
        for (int i = 0; i < 4; ++i) {
          const int r0 = m0 + 64 * wy + 16 * i + 4 * G;
#pragma unroll
          for (int v = 0; v < 4; ++v) {
            float z = acc[i][j][v] + bv;
            gate[(size_t)(r0 + v) * DI + c] = (short)f2bf(silu_f(z));
          }
        }
      }
      __syncthreads();   // protect LDS before next tile's staging
    }
  }
}

// ---------------- launch ----------------
extern "C" void kernel_launch(void* const* d_in, const int* in_sizes, int n_in,
                              void* d_out, int out_size, void* d_ws, size_t ws_size,
                              hipStream_t stream) {
  const float* x    = (const float*)d_in[0];   // [8,1024,1024]
  const float* h0   = (const float*)d_in[1];   // [8,2048]
  const float* win  = (const float*)d_in[2];   // [2048,1024]
  const float* wout = (const float*)d_in[3];   // [1024,2048]
  const float* ch   = (const float*)d_in[4];   // [2048]
  const float* cx   = (const float*)d_in[5];   // [2048]
  const float* bb   = (const float*)d_in[6];   // [2048]
  const float* wg   = (const float*)d_in[7];   // [2048,2048]
  const float* bg   = (const float*)d_in[8];   // [2048]
  float* out = (float*)d_out;                  // 8192*1024 output + 8*2048 h_final

  char* ws = (char*)d_ws;
  // liveness-packed workspace (peak 176,160,768 B)
  short* o_xb    = (short*)(ws + 0);           // 16.78M, dead after xproj gemm
  short* o_win   = (short*)(ws + 16777216);    // 4.19M,  dead after xproj gemm
  short* o_cx    = (short*)(ws + 20971520);    // 8.39M,  dead after pre gemm
  short* o_hseq  = (short*)(ws + 0);           // 33.55M, written by fused (above all dead)
  short* o_xproj = (short*)(ws + 33554432);    // 33.55M
  float* o_pre   = (float*)(ws + 67108864);    // 67.11M f32, dead after fused
  short* o_wout  = (short*)(ws + 67108864);    // 4.19M, cast AFTER fused (reuses pre)
  short* o_gate  = (short*)(ws + 134217728);   // 33.55M
  short* o_wg    = (short*)(ws + 167772160);   // 8.39M

  // 1) dtype conversions / circulant build
  cast_k<<<8192, 256, 0, stream>>>(x,   o_xb,  (BB * TT * DM) / 4);
  cast_k<<<2048, 256, 0, stream>>>(win, o_win, (DI * DM) / 4);
  cast_k<<<4096, 256, 0, stream>>>(wg,  o_wg,  (DI * DI) / 4);
  build_cx_k<<<2048, 256, 0, stream>>>(cx, o_cx);

  // 2) x_proj = x @ in_proj_w^T   [8192,2048] bf16
  gemm_k<<<dim3(DI / 128, ROWS / 128), 256, 0, stream>>>(
      o_xb, nullptr, o_win, ROWS, DI, DM, 0, nullptr, nullptr, o_xproj);

  // 3) pre = circ(c_x) x_proj + b   [8192,2048] f32
  gemm_k<<<dim3(DI / 128, ROWS / 128), 256, 0, stream>>>(
      o_xproj, nullptr, o_cx, ROWS, DI, DI, 1, bb, o_pre, nullptr);

  // 4) fused: scan (8 blocks) + gate GEMM (248 persistent blocks)
  fused_k<<<256, 512, 0, stream>>>(o_pre, h0, ch, o_hseq,
                                   out + (size_t)BB * TT * DM,
                                   o_xproj, o_wg, bg, o_gate);

  // 5) wout cast (into dead pre region)
  cast_k<<<2048, 256, 0, stream>>>(wout, o_wout, (DM * DI) / 4);

  // 6) output = (h_seq * gate) @ out_proj_w^T  — multiply fused into A-staging
  gemm_k<<<dim3(DM / 128, ROWS / 128), 256, 0, stream>>>(
      o_hseq, o_gate, o_wout, ROWS, DM, DI, 3, nullptr, out, nullptr);
}

// Round 5
// 2221.662 us; speedup vs baseline: 1.7016x; 1.0252x over previous
//
#include <hip/hip_runtime.h>
#include <cstdint>
#include <cstddef>

// ---------------- problem constants ----------------
#define DI 2048   // D_INNER
#define DM 1024   // DIM
#define BB 8      // batch
#define TT 1024   // seq len
#define ROWS (BB*TT)  // 8192
#define NSCAN 32  // scan blocks: 8 batches x 4 CUs

typedef short  short8 __attribute__((ext_vector_type(8)));
typedef float  f32x4  __attribute__((ext_vector_type(4)));

// ---------------- helpers ----------------
__device__ __forceinline__ unsigned short f2bf(float f) {
  unsigned int u = __builtin_bit_cast(unsigned int, f);
  u = u + 0x7fffu + ((u >> 16) & 1u);   // RNE
  return (unsigned short)(u >> 16);
}
__device__ __forceinline__ float fast_tanh(float x) {
  float ax = fabsf(x);
  float e  = __expf(-2.0f * ax);
  float t  = (1.0f - e) / (1.0f + e);
  return x < 0.0f ? -t : t;
}
__device__ __forceinline__ float silu_f(float z) {
  return z / (1.0f + __expf(-z));
}
__device__ __forceinline__ unsigned mulpk(unsigned a, unsigned b) {
  float a0 = __builtin_bit_cast(float, a << 16);
  float a1 = __builtin_bit_cast(float, a & 0xffff0000u);
  float b0 = __builtin_bit_cast(float, b << 16);
  float b1 = __builtin_bit_cast(float, b & 0xffff0000u);
  unsigned r0 = f2bf(a0 * b0), r1 = f2bf(a1 * b1);
  return r0 | (r1 << 16);
}
__device__ __forceinline__ uint4 pack8(const unsigned short* q) {
  uint4 p;
  p.x = (unsigned)q[0] | ((unsigned)q[1] << 16);
  p.y = (unsigned)q[2] | ((unsigned)q[3] << 16);
  p.z = (unsigned)q[4] | ((unsigned)q[5] << 16);
  p.w = (unsigned)q[6] | ((unsigned)q[7] << 16);
  return p;
}

// ---------------- f32 -> bf16 cast (4 elems/thread) ----------------
__global__ void cast_k(const float* __restrict__ s, short* __restrict__ d, int n4) {
  int i = blockIdx.x * 256 + threadIdx.x;
  if (i >= n4) return;
  float4 f = ((const float4*)s)[i];
  unsigned lo = (unsigned)f2bf(f.x) | ((unsigned)f2bf(f.y) << 16);
  unsigned hi = (unsigned)f2bf(f.z) | ((unsigned)f2bf(f.w) << 16);
  uint2 o; o.x = lo; o.y = hi;
  ((uint2*)d)[i] = o;
}

// ---------------- build circulant Bt for c_x: C[n][k] = c_x[(n-k) mod D] ----------------
__global__ void build_cx_k(const float* __restrict__ cx, short* __restrict__ C) {
  int tid = blockIdx.x * 256 + threadIdx.x;          // 0 .. 2048*256-1
  int n   = tid >> 8;
  int k0  = (tid & 255) * 8;
  unsigned short q[8];
#pragma unroll
  for (int j = 0; j < 8; ++j) q[j] = f2bf(cx[(n - (k0 + j)) & (DI - 1)]);
  *(uint4*)(C + (size_t)n * DI + k0) = pack8(q);
}

// ---------------- generic bf16 MFMA GEMM: C[M,N] = A[M,K] * Bt[N,K]^T ----------------
// A2 (optional): elementwise bf16 multiplier on A (fused cell = h*gate).
// mode 0: bf16 out; 1: f32 out + bias; 2: bf16 out + bias + silu; 3: f32 out
__global__ __launch_bounds__(256) void gemm_k(
    const short* __restrict__ A, const short* __restrict__ A2,
    const short* __restrict__ Bt,
    int M, int N, int K, int mode, const float* __restrict__ bias,
    float* __restrict__ outF, short* __restrict__ outH)
{
  __shared__ __align__(16) short As[128 * 40];
  __shared__ __align__(16) short Bs[128 * 40];
  const int tid  = threadIdx.x;
  const int m0   = blockIdx.y * 128, n0 = blockIdx.x * 128;
  const int wave = tid >> 6, lane = tid & 63;
  const int wy = wave >> 1, wx = wave & 1;
  const int l = lane & 15, G = lane >> 4;
  const int srow = tid >> 1, sseg = tid & 1;

  f32x4 acc[4][4];
#pragma unroll
  for (int i = 0; i < 4; ++i)
#pragma unroll
    for (int j = 0; j < 4; ++j) acc[i][j] = (f32x4){0.f, 0.f, 0.f, 0.f};

  for (int k0 = 0; k0 < K; k0 += 32) {
    if (k0) __syncthreads();
    const short* ga = A  + (size_t)(m0 + srow) * K + k0 + sseg * 16;
    const short* gb = Bt + (size_t)(n0 + srow) * K + k0 + sseg * 16;
    uint4 a0 = *(const uint4*)ga;
    uint4 a1 = *(const uint4*)(ga + 8);
    if (A2) {
      const short* g2 = A2 + (size_t)(m0 + srow) * K + k0 + sseg * 16;
      uint4 m0v = *(const uint4*)g2;
      uint4 m1v = *(const uint4*)(g2 + 8);
      a0.x = mulpk(a0.x, m0v.x); a0.y = mulpk(a0.y, m0v.y);
      a0.z = mulpk(a0.z, m0v.z); a0.w = mulpk(a0.w, m0v.w);
      a1.x = mulpk(a1.x, m1v.x); a1.y = mulpk(a1.y, m1v.y);
      a1.z = mulpk(a1.z, m1v.z); a1.w = mulpk(a1.w, m1v.w);
    }
    uint4 b0 = *(const uint4*)gb;
    uint4 b1 = *(const uint4*)(gb + 8);
    *(uint4*)&As[srow * 40 + sseg * 16]     = a0;
    *(uint4*)&As[srow * 40 + sseg * 16 + 8] = a1;
    *(uint4*)&Bs[srow * 40 + sseg * 16]     = b0;
    *(uint4*)&Bs[srow * 40 + sseg * 16 + 8] = b1;
    __syncthreads();
    short8 af[4], bfv[4];
#pragma unroll
    for (int i = 0; i < 4; ++i) af[i]  = *(const short8*)&As[(64 * wy + 16 * i + l) * 40 + 8 * G];
#pragma unroll
    for (int j = 0; j < 4; ++j) bfv[j] = *(const short8*)&Bs[(64 * wx + 16 * j + l) * 40 + 8 * G];
#pragma unroll
    for (int i = 0; i < 4; ++i)
#pragma unroll
      for (int j = 0; j < 4; ++j)
        acc[i][j] = __builtin_amdgcn_mfma_f32_16x16x32_bf16(af[i], bfv[j], acc[i][j], 0, 0, 0);
  }

#pragma unroll
  for (int j = 0; j < 4; ++j) {
    const int c = n0 + 64 * wx + 16 * j + l;
    float bv = 0.f;
    if (mode == 1 || mode == 2) bv = bias[c];
#pragma unroll
    for (int i = 0; i < 4; ++i) {
      const int r0 = m0 + 64 * wy + 16 * i + 4 * G;
#pragma unroll
      for (int v = 0; v < 4; ++v) {
        float z = acc[i][j][v] + bv;
        size_t off = (size_t)(r0 + v) * N + c;
        if (mode == 0)      outH[off] = (short)f2bf(z);
        else if (mode == 2) outH[off] = (short)f2bf(silu_f(z));
        else                outF[off] = z;
      }
    }
  }
}

// ---------------- fused: scan (blocks 0..31: 4 CUs per batch) + gate GEMM ----------------
// Multi-CU scan: per-CU matrix pipe is the wall (R2-R4 evidence), so split each
// batch's matvec across 4 CUs by OUTPUT quarter:
//   CU c of group b computes n in [512c, 512c+512):
//     n  = 512c + 32q + 16mt + r,   q in [0,16), mt in [0,2), r in [0,16)
//     k' = 512c + 32q + 32u + kappa (mod 2048), u in [0,64), kappa in [0,32)
//     A[r][kappa](mt,u) = c_h[(16mt + r - kappa - 32u) mod 2048]  (q,c-free; 16
//         diagonal classes/wave = 64 VGPR, static after unroll)
//     B[kappa][q](u)    = h[(512c + 32q + 32u + 8G + j) mod 2048] (swizzled LDS)
//   8 waves, wave w: u in [8w, 8w+8): 16 MFMAs 16x16x32, B-frag feeds both mt.
// Exchange per step: each CU publishes its h-quarter to hseq row t via
// agent-scope relaxed atomic stores (write-through to L3), per-wave vmcnt drained
// by __syncthreads, then thread 0 sets a per-CU flag (monotonic t+1) in the OUT
// buffer (scratch until gemm-6; zeroed by memset). Next step polls the 3 partner
// flags and rebuilds full h_lds from the global row (agent-scope loads, no stale
// cache). hseq publication doubles as the required hseq output: zero extra data.
__global__ __launch_bounds__(512, 2) void fused_k(
    const float* __restrict__ pre, const float* __restrict__ h0,
    const float* __restrict__ ch, short* __restrict__ hseq,
    float* __restrict__ hfin,
    const short* __restrict__ xproj, const short* __restrict__ wg,
    const float* __restrict__ bg, short* __restrict__ gate,
    unsigned* __restrict__ flags)
{
  __shared__ __align__(16) char smem[86016];   // pad: force 1 block/CU
  const int bid = blockIdx.x;
  const int tid = threadIdx.x;

  if (bid < NSCAN) {
    // ================= scan path (quarter-output per CU) =================
    short* h_lds = (short*)smem;             // 2048 bf16, swizzled 8-elem blocks
    float* part  = (float*)(smem + 4096);    // 8 x 512 f32, swizzled f32x4 blocks
    const int b = bid >> 2, c = bid & 3;
    const int w = tid >> 6, lane = tid & 63;
    const int q = lane & 15, G = lane >> 4;
    const float* preB = pre + (size_t)b * TT * DI + 512 * c;
    unsigned* myflag = flags + (4 * b + c) * 32;

    // A fragments: 16 diagonal classes, idx = mt - 2s + 14 (s = local u)
    // elem(lane,j) = c_h[(16*(idx-14) + q - 8G - j - 256w) mod D]
    short8 av[16];
#pragma unroll
    for (int idx = 0; idx < 16; ++idx) {
      const int base = 16 * (idx - 14) + q - 8 * G - 256 * w;
      short8 v;
#pragma unroll
      for (int j = 0; j < 8; ++j)
        v[j] = (short)f2bf(ch[(base - j) & (DI - 1)]);
      av[idx] = v;
    }

    // init full h_lds from h0 (swizzled): thread writes elems 4*tid..4*tid+3
    {
      float4 hv = *(const float4*)(h0 + b * DI + 4 * tid);
      unsigned lo = (unsigned)f2bf(hv.x) | ((unsigned)f2bf(hv.y) << 16);
      unsigned hi = (unsigned)f2bf(hv.z) | ((unsigned)f2bf(hv.w) << 16);
      const int blk = tid >> 1;
      const int pb  = blk ^ ((blk >> 4) & 7);
      uint2 wv; wv.x = lo; wv.y = hi;
      *(uint2*)&h_lds[pb * 8 + 4 * (tid & 1)] = wv;
    }
    float pcur = preB[tid];   // pre[b][0][512c + tid]

    const int bbase = 64 * c + 32 * w + 4 * q + G;  // B-frag block base (s=0)

    for (int t = 0; t < TT; ++t) {
      if (t) {
        // poll 3 partner flags (lanes 0-2), wave-wide
        const int pc = (lane < 3) ? (lane + (lane >= c ? 1 : 0)) : 0;
        const unsigned* fp = flags + (4 * b + pc) * 32;
        while (true) {
          unsigned v = __hip_atomic_load(fp, __ATOMIC_RELAXED, __HIP_MEMORY_SCOPE_AGENT);
          bool ok = (lane < 3) ? (v >= (unsigned)t) : true;
          if (__all(ok)) break;
          __builtin_amdgcn_s_sleep(2);
        }
        // rebuild full h_lds from hseq row t-1 (agent loads: no stale cache)
        const unsigned* rowU = (const unsigned*)(hseq + (size_t)(b * TT + t - 1) * DI);
        unsigned d0 = __hip_atomic_load(rowU + tid,       __ATOMIC_RELAXED, __HIP_MEMORY_SCOPE_AGENT);
        unsigned d1 = __hip_atomic_load(rowU + tid + 512, __ATOMIC_RELAXED, __HIP_MEMORY_SCOPE_AGENT);
        const int blkA = tid >> 2,        pbA = blkA ^ ((blkA >> 4) & 7);
        const int blkB = (tid + 512) >> 2, pbB = blkB ^ ((blkB >> 4) & 7);
        *(unsigned*)&h_lds[pbA * 8 + 2 * (tid & 3)] = d0;
        *(unsigned*)&h_lds[pbB * 8 + 2 * (tid & 3)] = d1;
      }
      __syncthreads();   // bar C: h_lds ready

      // prefetch next pre element (1 f32/thread)
      float pf = preB[(size_t)(t + 1 < TT ? t + 1 : t) * DI + tid];

      // ---- matvec quarter: 16 MFMAs (2 mt x 8 s), B-frag feeds both mt ----
      f32x4 acc0 = (f32x4){0.f, 0.f, 0.f, 0.f};
      f32x4 acc1 = (f32x4){0.f, 0.f, 0.f, 0.f};
#pragma unroll
      for (int s = 0; s < 8; ++s) {
        const int blk = (bbase + 4 * s) & 255;
        const int pb  = blk ^ ((blk >> 4) & 7);
        short8 bv = *(const short8*)&h_lds[pb * 8];
        acc0 = __builtin_amdgcn_mfma_f32_16x16x32_bf16(av[14 - 2 * s], bv, acc0, 0, 0, 0);
        acc1 = __builtin_amdgcn_mfma_f32_16x16x32_bf16(av[15 - 2 * s], bv, acc1, 0, 0, 0);
      }
      // partial write: n_loc = 32q + 16mt + 4G + v -> f4 idx f = 8q + 4mt + G
      {
        float* pk = part + (w << 9);
        const int f0 = 8 * q + G,     p0 = f0 ^ ((f0 >> 4) & 7);
        const int f1 = 8 * q + 4 + G, p1 = f1 ^ ((f1 >> 4) & 7);
        *(f32x4*)&pk[4 * p0] = acc0;
        *(f32x4*)&pk[4 * p1] = acc1;
      }
      __syncthreads();   // bar A: partials visible

      // ---- epilogue: 1 output/thread (n_loc = tid) ----
      {
        const int f = tid >> 2, vv = tid & 3;
        const int pfz = f ^ ((f >> 4) & 7);
        const int off = 4 * pfz + vv;
        float z = ((part[off] + part[512 + off]) + (part[1024 + off] + part[1536 + off]))
                + ((part[2048 + off] + part[2560 + off]) + (part[3072 + off] + part[3584 + off]))
                + pcur;
        float th = fast_tanh(z);
        unsigned hv = (unsigned)f2bf(th);
        unsigned other = (unsigned)__shfl_xor((int)hv, 1);
        if (!(lane & 1)) {
          unsigned dw = (hv & 0xffffu) | (other << 16);
          unsigned* rowO = (unsigned*)(hseq + (size_t)(b * TT + t) * DI);
          __hip_atomic_store(rowO + 256 * c + (tid >> 1), dw,
                             __ATOMIC_RELAXED, __HIP_MEMORY_SCOPE_AGENT);
        }
        if (t == TT - 1) hfin[b * DI + 512 * c + tid] = th;
      }
      __syncthreads();   // bar B: all waves' publish stores vmcnt-drained
      if (tid == 0)
        __hip_atomic_store(myflag, (unsigned)(t + 1),
                           __ATOMIC_RELAXED, __HIP_MEMORY_SCOPE_AGENT);
      pcur = pf;
    }
  } else {
    // ================= gate GEMM path (persistent tiles) =================
    // tile = 256 rows x 128 cols; 8 waves: wy in [0,4), wx in [0,2)
    short* As = (short*)smem;              // 256 x 40
    short* Bs = (short*)(smem + 20480);    // 128 x 40
    const int wid = tid >> 6, lane = tid & 63;
    const int wy = wid >> 1, wx = wid & 1;
    const int l = lane & 15, G = lane >> 4;

    for (int tile = bid - NSCAN; tile < 512; tile += (256 - NSCAN)) {
      const int m0 = (tile & 31) * 256, n0 = (tile >> 5) * 128;
      f32x4 acc[4][4];
#pragma unroll
      for (int i = 0; i < 4; ++i)
#pragma unroll
        for (int j = 0; j < 4; ++j) acc[i][j] = (f32x4){0.f, 0.f, 0.f, 0.f};

      for (int k0 = 0; k0 < DI; k0 += 32) {
        __syncthreads();
        const short* ga = xproj + (size_t)(m0 + (tid >> 1)) * DI + k0 + (tid & 1) * 16;
        const short* gb = wg    + (size_t)(n0 + (tid >> 2)) * DI + k0 + (tid & 3) * 8;
        uint4 a0 = *(const uint4*)ga;
        uint4 a1 = *(const uint4*)(ga + 8);
        uint4 b0 = *(const uint4*)gb;
        *(uint4*)&As[(tid >> 1) * 40 + (tid & 1) * 16]     = a0;
        *(uint4*)&As[(tid >> 1) * 40 + (tid & 1) * 16 + 8] = a1;
        *(uint4*)&Bs[(tid >> 2) * 40 + (tid & 3) * 8]      = b0;
        __syncthreads();
        short8 af[4], bfv[4];
#pragma unroll
        for (int i = 0; i < 4; ++i) af[i]  = *(const short8*)&As[(64 * wy + 16 * i + l) * 40 + 8 * G];
#pragma unroll
        for (int j = 0; j < 4; ++j) bfv[j] = *(const short8*)&Bs[(64 * wx + 16 * j + l) * 40 + 8 * G];
#pragma unroll
        for (int i = 0; i < 4; ++i)
#pragma unroll
          for (int j = 0; j < 4; ++j)
            acc[i][j] = __builtin_amdgcn_mfma_f32_16x16x32_bf16(af[i], bfv[j], acc[i][j], 0, 0, 0);
      }
#pragma unroll
      for (int j = 0; j < 4; ++j) {
        const int cidx = n0 + 64 * wx + 16 * j + l;
        const float bv = bg[cidx];
#pragma unroll
        for (int i = 0; i < 4; ++i) {
          const int r0 = m0 + 64 * wy + 16 * i + 4 * G;
#pragma unroll
          for (int v = 0; v < 4; ++v) {
            float z = acc[i][j][v] + bv;
            gate[(size_t)(r0 + v) * DI + cidx] = (short)f2bf(silu_f(z));
          }
        }
      }
      __syncthreads();   // protect LDS before next tile's staging
    }
  }
}

// ---------------- launch ----------------
extern "C" void kernel_launch(void* const* d_in, const int* in_sizes, int n_in,
                              void* d_out, int out_size, void* d_ws, size_t ws_size,
                              hipStream_t stream) {
  const float* x    = (const float*)d_in[0];   // [8,1024,1024]
  const float* h0   = (const float*)d_in[1];   // [8,2048]
  const float* win  = (const float*)d_in[2];   // [2048,1024]
  const float* wout = (const float*)d_in[3];   // [1024,2048]
  const float* ch   = (const float*)d_in[4];   // [2048]
  const float* cx   = (const float*)d_in[5];   // [2048]
  const float* bb   = (const float*)d_in[6];   // [2048]
  const float* wg   = (const float*)d_in[7];   // [2048,2048]
  const float* bg   = (const float*)d_in[8];   // [2048]
  float* out = (float*)d_out;                  // 8192*1024 output + 8*2048 h_final

  char* ws = (char*)d_ws;
  // liveness-packed workspace (peak 176,160,768 B)
  short* o_xb    = (short*)(ws + 0);           // 16.78M, dead after xproj gemm
  short* o_win   = (short*)(ws + 16777216);    // 4.19M,  dead after xproj gemm
  short* o_cx    = (short*)(ws + 20971520);    // 8.39M,  dead after pre gemm
  short* o_hseq  = (short*)(ws + 0);           // 33.55M, written by fused (above all dead)
  short* o_xproj = (short*)(ws + 33554432);    // 33.55M
  float* o_pre   = (float*)(ws + 67108864);    // 67.11M f32, dead after fused
  short* o_wout  = (short*)(ws + 67108864);    // 4.19M, cast AFTER fused (reuses pre)
  short* o_gate  = (short*)(ws + 134217728);   // 33.55M
  short* o_wg    = (short*)(ws + 167772160);   // 8.39M

  // 1) dtype conversions / circulant build
  cast_k<<<8192, 256, 0, stream>>>(x,   o_xb,  (BB * TT * DM) / 4);
  cast_k<<<2048, 256, 0, stream>>>(win, o_win, (DI * DM) / 4);
  cast_k<<<4096, 256, 0, stream>>>(wg,  o_wg,  (DI * DI) / 4);
  build_cx_k<<<2048, 256, 0, stream>>>(cx, o_cx);

  // 2) x_proj = x @ in_proj_w^T   [8192,2048] bf16
  gemm_k<<<dim3(DI / 128, ROWS / 128), 256, 0, stream>>>(
      o_xb, nullptr, o_win, ROWS, DI, DM, 0, nullptr, nullptr, o_xproj);

  // 3) pre = circ(c_x) x_proj + b   [8192,2048] f32
  gemm_k<<<dim3(DI / 128, ROWS / 128), 256, 0, stream>>>(
      o_xproj, nullptr, o_cx, ROWS, DI, DI, 1, bb, o_pre, nullptr);

  // 3b) zero the scan sync flags (live in out[] — scratch until gemm-6)
  hipMemsetAsync(d_out, 0, 4096, stream);

  // 4) fused: scan (32 blocks = 8 batches x 4 CUs) + gate GEMM (224 blocks)
  fused_k<<<256, 512, 0, stream>>>(o_pre, h0, ch, o_hseq,
                                   out + (size_t)BB * TT * DM,
                                   o_xproj, o_wg, bg, o_gate,
                                   (unsigned*)d_out);

  // 5) wout cast (into dead pre region)
  cast_k<<<2048, 256, 0, stream>>>(wout, o_wout, (DM * DI) / 4);

  // 6) output = (h_seq * gate) @ out_proj_w^T  — multiply fused into A-staging
  gemm_k<<<dim3(DM / 128, ROWS / 128), 256, 0, stream>>>(
      o_hseq, o_gate, o_wout, ROWS, DM, DI, 3, nullptr, out, nullptr);
}

// Round 6
// 2058.057 us; speedup vs baseline: 1.8369x; 1.0795x over previous
//
#include <hip/hip_runtime.h>
#include <cstdint>
#include <cstddef>

// ---------------- problem constants ----------------
#define DI 2048   // D_INNER
#define DM 1024   // DIM
#define BB 8      // batch
#define TT 1024   // seq len
#define ROWS (BB*TT)  // 8192
#define NSCAN 32  // scan blocks: 8 batches x 4 CUs

typedef short  short8 __attribute__((ext_vector_type(8)));
typedef float  f32x4  __attribute__((ext_vector_type(4)));
typedef unsigned u32x4 __attribute__((ext_vector_type(4)));

// ---------------- helpers ----------------
__device__ __forceinline__ unsigned short f2bf(float f) {
  unsigned int u = __builtin_bit_cast(unsigned int, f);
  u = u + 0x7fffu + ((u >> 16) & 1u);   // RNE
  return (unsigned short)(u >> 16);
}
__device__ __forceinline__ float fast_tanh(float x) {
  float ax = fabsf(x);
  float e  = __expf(-2.0f * ax);
  float t  = (1.0f - e) / (1.0f + e);
  return x < 0.0f ? -t : t;
}
__device__ __forceinline__ float silu_f(float z) {
  return z / (1.0f + __expf(-z));
}
__device__ __forceinline__ unsigned mulpk(unsigned a, unsigned b) {
  float a0 = __builtin_bit_cast(float, a << 16);
  float a1 = __builtin_bit_cast(float, a & 0xffff0000u);
  float b0 = __builtin_bit_cast(float, b << 16);
  float b1 = __builtin_bit_cast(float, b & 0xffff0000u);
  unsigned r0 = f2bf(a0 * b0), r1 = f2bf(a1 * b1);
  return r0 | (r1 << 16);
}
__device__ __forceinline__ uint4 pack8(const unsigned short* q) {
  uint4 p;
  p.x = (unsigned)q[0] | ((unsigned)q[1] << 16);
  p.y = (unsigned)q[2] | ((unsigned)q[3] << 16);
  p.z = (unsigned)q[4] | ((unsigned)q[5] << 16);
  p.w = (unsigned)q[6] | ((unsigned)q[7] << 16);
  return p;
}

// ---- self-flagging 16B packet ops: single-transaction L3 load/store ----
// sc0 sc1 = device-coherent (bypass L1/L2) on gfx950.
__device__ __forceinline__ u32x4 ld_packet(const void* p) {
  u32x4 r;
  asm volatile("global_load_dwordx4 %0, %1, off sc0 sc1\n\ts_waitcnt vmcnt(0)"
               : "=v"(r) : "v"(p) : "memory");
  return r;
}
__device__ __forceinline__ void st_packet(void* p, u32x4 v) {
  asm volatile("global_store_dwordx4 %0, %1, off sc0 sc1"
               :: "v"(p), "v"(v) : "memory");
}

// ---------------- f32 -> bf16 cast (4 elems/thread) ----------------
__global__ void cast_k(const float* __restrict__ s, short* __restrict__ d, int n4) {
  int i = blockIdx.x * 256 + threadIdx.x;
  if (i >= n4) return;
  float4 f = ((const float4*)s)[i];
  unsigned lo = (unsigned)f2bf(f.x) | ((unsigned)f2bf(f.y) << 16);
  unsigned hi = (unsigned)f2bf(f.z) | ((unsigned)f2bf(f.w) << 16);
  uint2 o; o.x = lo; o.y = hi;
  ((uint2*)d)[i] = o;
}

// ---------------- build circulant Bt for c_x: C[n][k] = c_x[(n-k) mod D] ----------------
__global__ void build_cx_k(const float* __restrict__ cx, short* __restrict__ C) {
  int tid = blockIdx.x * 256 + threadIdx.x;          // 0 .. 2048*256-1
  int n   = tid >> 8;
  int k0  = (tid & 255) * 8;
  unsigned short q[8];
#pragma unroll
  for (int j = 0; j < 8; ++j) q[j] = f2bf(cx[(n - (k0 + j)) & (DI - 1)]);
  *(uint4*)(C + (size_t)n * DI + k0) = pack8(q);
}

// ---------------- generic bf16 MFMA GEMM: C[M,N] = A[M,K] * Bt[N,K]^T ----------------
// A2 (optional): elementwise bf16 multiplier on A (fused cell = h*gate).
// mode 0: bf16 out; 1: f32 out + bias; 2: bf16 out + bias + silu; 3: f32 out
__global__ __launch_bounds__(256) void gemm_k(
    const short* __restrict__ A, const short* __restrict__ A2,
    const short* __restrict__ Bt,
    int M, int N, int K, int mode, const float* __restrict__ bias,
    float* __restrict__ outF, short* __restrict__ outH)
{
  __shared__ __align__(16) short As[128 * 40];
  __shared__ __align__(16) short Bs[128 * 40];
  const int tid  = threadIdx.x;
  const int m0   = blockIdx.y * 128, n0 = blockIdx.x * 128;
  const int wave = tid >> 6, lane = tid & 63;
  const int wy = wave >> 1, wx = wave & 1;
  const int l = lane & 15, G = lane >> 4;
  const int srow = tid >> 1, sseg = tid & 1;

  f32x4 acc[4][4];
#pragma unroll
  for (int i = 0; i < 4; ++i)
#pragma unroll
    for (int j = 0; j < 4; ++j) acc[i][j] = (f32x4){0.f, 0.f, 0.f, 0.f};

  for (int k0 = 0; k0 < K; k0 += 32) {
    if (k0) __syncthreads();
    const short* ga = A  + (size_t)(m0 + srow) * K + k0 + sseg * 16;
    const short* gb = Bt + (size_t)(n0 + srow) * K + k0 + sseg * 16;
    uint4 a0 = *(const uint4*)ga;
    uint4 a1 = *(const uint4*)(ga + 8);
    if (A2) {
      const short* g2 = A2 + (size_t)(m0 + srow) * K + k0 + sseg * 16;
      uint4 m0v = *(const uint4*)g2;
      uint4 m1v = *(const uint4*)(g2 + 8);
      a0.x = mulpk(a0.x, m0v.x); a0.y = mulpk(a0.y, m0v.y);
      a0.z = mulpk(a0.z, m0v.z); a0.w = mulpk(a0.w, m0v.w);
      a1.x = mulpk(a1.x, m1v.x); a1.y = mulpk(a1.y, m1v.y);
      a1.z = mulpk(a1.z, m1v.z); a1.w = mulpk(a1.w, m1v.w);
    }
    uint4 b0 = *(const uint4*)gb;
    uint4 b1 = *(const uint4*)(gb + 8);
    *(uint4*)&As[srow * 40 + sseg * 16]     = a0;
    *(uint4*)&As[srow * 40 + sseg * 16 + 8] = a1;
    *(uint4*)&Bs[srow * 40 + sseg * 16]     = b0;
    *(uint4*)&Bs[srow * 40 + sseg * 16 + 8] = b1;
    __syncthreads();
    short8 af[4], bfv[4];
#pragma unroll
    for (int i = 0; i < 4; ++i) af[i]  = *(const short8*)&As[(64 * wy + 16 * i + l) * 40 + 8 * G];
#pragma unroll
    for (int j = 0; j < 4; ++j) bfv[j] = *(const short8*)&Bs[(64 * wx + 16 * j + l) * 40 + 8 * G];
#pragma unroll
    for (int i = 0; i < 4; ++i)
#pragma unroll
      for (int j = 0; j < 4; ++j)
        acc[i][j] = __builtin_amdgcn_mfma_f32_16x16x32_bf16(af[i], bfv[j], acc[i][j], 0, 0, 0);
  }

#pragma unroll
  for (int j = 0; j < 4; ++j) {
    const int c = n0 + 64 * wx + 16 * j + l;
    float bv = 0.f;
    if (mode == 1 || mode == 2) bv = bias[c];
#pragma unroll
    for (int i = 0; i < 4; ++i) {
      const int r0 = m0 + 64 * wy + 16 * i + 4 * G;
#pragma unroll
      for (int v = 0; v < 4; ++v) {
        float z = acc[i][j][v] + bv;
        size_t off = (size_t)(r0 + v) * N + c;
        if (mode == 0)      outH[off] = (short)f2bf(z);
        else if (mode == 2) outH[off] = (short)f2bf(silu_f(z));
        else                outF[off] = z;
      }
    }
  }
}

// ---------------- fused: scan (blocks 0..31: 4 CUs per batch) + gate GEMM ----------------
// Multi-CU scan, SELF-FLAGGING exchange (1 L3 round trip):
//   CU c of batch b computes output quarter n in [512c, 512c+512) (R5 math,
//   verified). Per step each CU publishes its quarter as 128 16-byte packets
//   {d0, d1, tag=t, 0} via single global_store_dwordx4 sc0 sc1 (one L3
//   transaction -> tag/data consistent). Partners poll each packet with single
//   global_load_dwordx4 sc0 sc1 until tag==t: no separate flag, no flag RT,
//   no poll->load serialization. Double-buffered by t parity; exact-tag match
//   + the tag happens-before chain make writer lapping impossible. Own quarter
//   goes directly into swizzled h_lds from the epilogue. 2 barriers/step.
__global__ __launch_bounds__(512, 2) void fused_k(
    const float* __restrict__ pre, const float* __restrict__ h0,
    const float* __restrict__ ch, short* __restrict__ hseq,
    float* __restrict__ hfin,
    const short* __restrict__ xproj, const short* __restrict__ wg,
    const float* __restrict__ bg, short* __restrict__ gate,
    u32x4* __restrict__ exbuf)   // [2][BB][4][128] 16B packets (in d_out scratch)
{
  __shared__ __align__(16) char smem[86016];   // pad: force 1 block/CU
  const int bid = blockIdx.x;
  const int tid = threadIdx.x;

  if (bid < NSCAN) {
    // ================= scan path (quarter-output per CU) =================
    short* h_lds = (short*)smem;             // 2048 bf16, swizzled 8-elem blocks
    float* part  = (float*)(smem + 4096);    // 8 x 512 f32, swizzled f32x4 blocks
    const int b = bid >> 2, c = bid & 3;
    const int w = tid >> 6, lane = tid & 63;
    const int q = lane & 15, G = lane >> 4;
    const float* preB = pre + (size_t)b * TT * DI + 512 * c;

    // A fragments: 16 diagonal classes, idx = mt - 2s + 14 (s = local u)
    short8 av[16];
#pragma unroll
    for (int idx = 0; idx < 16; ++idx) {
      const int base = 16 * (idx - 14) + q - 8 * G - 256 * w;
      short8 v;
#pragma unroll
      for (int j = 0; j < 8; ++j)
        v[j] = (short)f2bf(ch[(base - j) & (DI - 1)]);
      av[idx] = v;
    }

    // init full h_lds from h0 (swizzled): thread writes elems 4*tid..4*tid+3
    {
      float4 hv = *(const float4*)(h0 + b * DI + 4 * tid);
      unsigned lo = (unsigned)f2bf(hv.x) | ((unsigned)f2bf(hv.y) << 16);
      unsigned hi = (unsigned)f2bf(hv.z) | ((unsigned)f2bf(hv.w) << 16);
      const int blk = tid >> 1;
      const int pb  = blk ^ ((blk >> 4) & 7);
      uint2 wv; wv.x = lo; wv.y = hi;
      *(uint2*)&h_lds[pb * 8 + 4 * (tid & 1)] = wv;
    }
    float pcur = preB[tid];   // pre[b][0][512c + tid]

    const int bbase = 64 * c + 32 * w + 4 * q + G;  // B-frag block base (s=0)

    for (int t = 0; t < TT; ++t) {
      // prefetch next pre element (independent; in flight during poll)
      float pf = preB[(size_t)(t + 1 < TT ? t + 1 : t) * DI + tid];

      // ---- rebuild partner quarters of h_lds (threads 0..383) ----
      if (t && tid < 384) {
        const int pci = tid >> 7;                       // 0..2
        const int pc  = pci + (pci >= c ? 1 : 0);       // partner quarter
        const int p   = tid & 127;                      // packet index
        u32x4* addr = exbuf + ((size_t)(((t - 1) & 1) * BB + b) * 4 + pc) * 128 + p;
        u32x4 pkt;
        do { pkt = ld_packet(addr); } while (pkt[2] != (unsigned)(t - 1));
        const int n   = 512 * pc + 4 * p;
        const int blk = n >> 3, pb = blk ^ ((blk >> 4) & 7);
        uint2 wv; wv.x = pkt[0]; wv.y = pkt[1];
        *(uint2*)&h_lds[pb * 8 + 4 * (p & 1)] = wv;
      }
      __syncthreads();   // bar C: h_lds = h_t complete

      // ---- matvec quarter: 16 MFMAs (2 mt x 8 s), B-frag feeds both mt ----
      f32x4 acc0 = (f32x4){0.f, 0.f, 0.f, 0.f};
      f32x4 acc1 = (f32x4){0.f, 0.f, 0.f, 0.f};
#pragma unroll
      for (int s = 0; s < 8; ++s) {
        const int blk = (bbase + 4 * s) & 255;
        const int pb  = blk ^ ((blk >> 4) & 7);
        short8 bv = *(const short8*)&h_lds[pb * 8];
        acc0 = __builtin_amdgcn_mfma_f32_16x16x32_bf16(av[14 - 2 * s], bv, acc0, 0, 0, 0);
        acc1 = __builtin_amdgcn_mfma_f32_16x16x32_bf16(av[15 - 2 * s], bv, acc1, 0, 0, 0);
      }
      // partial write: f4 idx f = 8q + 4mt + G, swizzled
      {
        float* pk = part + (w << 9);
        const int f0 = 8 * q + G,     p0 = f0 ^ ((f0 >> 4) & 7);
        const int f1 = 8 * q + 4 + G, p1 = f1 ^ ((f1 >> 4) & 7);
        *(f32x4*)&pk[4 * p0] = acc0;
        *(f32x4*)&pk[4 * p1] = acc1;
      }
      __syncthreads();   // bar A: partials visible

      // ---- epilogue: 1 output/thread (n_loc = tid) ----
      {
        const int f = tid >> 2, vv = tid & 3;
        const int pfz = f ^ ((f >> 4) & 7);
        const int off = 4 * pfz + vv;
        float z = ((part[off] + part[512 + off]) + (part[1024 + off] + part[1536 + off]))
                + ((part[2048 + off] + part[2560 + off]) + (part[3072 + off] + part[3584 + off]))
                + pcur;
        float th = fast_tanh(z);
        unsigned hvu = (unsigned)f2bf(th);
        unsigned o1  = (unsigned)__shfl_xor((int)hvu, 1);
        unsigned dw  = (hvu & 0xffffu) | (o1 << 16);        // valid on even lanes
        unsigned dw2 = (unsigned)__shfl_xor((int)dw, 2);    // lane%4==0: next dword
        // publish own quarter packets FIRST (latency-critical for partners)
        if (t < TT - 1 && (lane & 3) == 0) {
          u32x4 pkt; pkt[0] = dw; pkt[1] = dw2; pkt[2] = (unsigned)t; pkt[3] = 0u;
          u32x4* addr = exbuf + ((size_t)((t & 1) * BB + b) * 4 + c) * 128 + (tid >> 2);
          st_packet(addr, pkt);
        }
        // own quarter into h_lds (disjoint from partner rebuild regions)
        if (!(lane & 1)) {
          const int n   = 512 * c + tid;
          const int blk = n >> 3, pb = blk ^ ((blk >> 4) & 7);
          *(unsigned*)&h_lds[pb * 8 + (n & 6)] = dw;
          // hseq output row (plain store, off critical path)
          unsigned* rowO = (unsigned*)(hseq + (size_t)(b * TT + t) * DI);
          rowO[256 * c + (tid >> 1)] = dw;
        }
        if (t == TT - 1) hfin[b * DI + 512 * c + tid] = th;
      }
      pcur = pf;
      // no bar B: next iter's rebuild writes partner regions (disjoint from
      // this epilogue's own-region writes); bar C orders everything for matvec
    }
  } else {
    // ================= gate GEMM path (persistent tiles) =================
    // tile = 256 rows x 128 cols; 8 waves: wy in [0,4), wx in [0,2)
    short* As = (short*)smem;              // 256 x 40
    short* Bs = (short*)(smem + 20480);    // 128 x 40
    const int wid = tid >> 6, lane = tid & 63;
    const int wy = wid >> 1, wx = wid & 1;
    const int l = lane & 15, G = lane >> 4;

    for (int tile = bid - NSCAN; tile < 512; tile += (256 - NSCAN)) {
      const int m0 = (tile & 31) * 256, n0 = (tile >> 5) * 128;
      f32x4 acc[4][4];
#pragma unroll
      for (int i = 0; i < 4; ++i)
#pragma unroll
        for (int j = 0; j < 4; ++j) acc[i][j] = (f32x4){0.f, 0.f, 0.f, 0.f};

      for (int k0 = 0; k0 < DI; k0 += 32) {
        __syncthreads();
        const short* ga = xproj + (size_t)(m0 + (tid >> 1)) * DI + k0 + (tid & 1) * 16;
        const short* gb = wg    + (size_t)(n0 + (tid >> 2)) * DI + k0 + (tid & 3) * 8;
        uint4 a0 = *(const uint4*)ga;
        uint4 a1 = *(const uint4*)(ga + 8);
        uint4 b0 = *(const uint4*)gb;
        *(uint4*)&As[(tid >> 1) * 40 + (tid & 1) * 16]     = a0;
        *(uint4*)&As[(tid >> 1) * 40 + (tid & 1) * 16 + 8] = a1;
        *(uint4*)&Bs[(tid >> 2) * 40 + (tid & 3) * 8]      = b0;
        __syncthreads();
        short8 af[4], bfv[4];
#pragma unroll
        for (int i = 0; i < 4; ++i) af[i]  = *(const short8*)&As[(64 * wy + 16 * i + l) * 40 + 8 * G];
#pragma unroll
        for (int j = 0; j < 4; ++j) bfv[j] = *(const short8*)&Bs[(64 * wx + 16 * j + l) * 40 + 8 * G];
#pragma unroll
        for (int i = 0; i < 4; ++i)
#pragma unroll
          for (int j = 0; j < 4; ++j)
            acc[i][j] = __builtin_amdgcn_mfma_f32_16x16x32_bf16(af[i], bfv[j], acc[i][j], 0, 0, 0);
      }
#pragma unroll
      for (int j = 0; j < 4; ++j) {
        const int cidx = n0 + 64 * wx + 16 * j + l;
        const float bv = bg[cidx];
#pragma unroll
        for (int i = 0; i < 4; ++i) {
          const int r0 = m0 + 64 * wy + 16 * i + 4 * G;
#pragma unroll
          for (int v = 0; v < 4; ++v) {
            float z = acc[i][j][v] + bv;
            gate[(size_t)(r0 + v) * DI + cidx] = (short)f2bf(silu_f(z));
          }
        }
      }
      __syncthreads();   // protect LDS before next tile's staging
    }
  }
}

// ---------------- launch ----------------
extern "C" void kernel_launch(void* const* d_in, const int* in_sizes, int n_in,
                              void* d_out, int out_size, void* d_ws, size_t ws_size,
                              hipStream_t stream) {
  const float* x    = (const float*)d_in[0];   // [8,1024,1024]
  const float* h0   = (const float*)d_in[1];   // [8,2048]
  const float* win  = (const float*)d_in[2];   // [2048,1024]
  const float* wout = (const float*)d_in[3];   // [1024,2048]
  const float* ch   = (const float*)d_in[4];   // [2048]
  const float* cx   = (const float*)d_in[5];   // [2048]
  const float* bb   = (const float*)d_in[6];   // [2048]
  const float* wg   = (const float*)d_in[7];   // [2048,2048]
  const float* bg   = (const float*)d_in[8];   // [2048]
  float* out = (float*)d_out;                  // 8192*1024 output + 8*2048 h_final

  char* ws = (char*)d_ws;
  // liveness-packed workspace (peak 176,160,768 B)
  short* o_xb    = (short*)(ws + 0);           // 16.78M, dead after xproj gemm
  short* o_win   = (short*)(ws + 16777216);    // 4.19M,  dead after xproj gemm
  short* o_cx    = (short*)(ws + 20971520);    // 8.39M,  dead after pre gemm
  short* o_hseq  = (short*)(ws + 0);           // 33.55M, written by fused (above all dead)
  short* o_xproj = (short*)(ws + 33554432);    // 33.55M
  float* o_pre   = (float*)(ws + 67108864);    // 67.11M f32, dead after fused
  short* o_wout  = (short*)(ws + 67108864);    // 4.19M, cast AFTER fused (reuses pre)
  short* o_gate  = (short*)(ws + 134217728);   // 33.55M
  short* o_wg    = (short*)(ws + 167772160);   // 8.39M

  // 1) dtype conversions / circulant build
  cast_k<<<8192, 256, 0, stream>>>(x,   o_xb,  (BB * TT * DM) / 4);
  cast_k<<<2048, 256, 0, stream>>>(win, o_win, (DI * DM) / 4);
  cast_k<<<4096, 256, 0, stream>>>(wg,  o_wg,  (DI * DI) / 4);
  build_cx_k<<<2048, 256, 0, stream>>>(cx, o_cx);

  // 2) x_proj = x @ in_proj_w^T   [8192,2048] bf16
  gemm_k<<<dim3(DI / 128, ROWS / 128), 256, 0, stream>>>(
      o_xb, nullptr, o_win, ROWS, DI, DM, 0, nullptr, nullptr, o_xproj);

  // 3) pre = circ(c_x) x_proj + b   [8192,2048] f32
  gemm_k<<<dim3(DI / 128, ROWS / 128), 256, 0, stream>>>(
      o_xproj, nullptr, o_cx, ROWS, DI, DI, 1, bb, o_pre, nullptr);

  // 3b) invalidate exchange packets (tags 0xFFFFFFFF never match any step).
  //     exbuf lives in out[] scratch: [2][8][4][128] x 16B = 128 KiB,
  //     fully overwritten later by gemm-6.
  hipMemsetAsync(d_out, 0xFF, 2 * BB * 4 * 128 * 16, stream);

  // 4) fused: scan (32 blocks = 8 batches x 4 CUs) + gate GEMM (224 blocks)
  fused_k<<<256, 512, 0, stream>>>(o_pre, h0, ch, o_hseq,
                                   out + (size_t)BB * TT * DM,
                                   o_xproj, o_wg, bg, o_gate,
                                   (u32x4*)d_out);

  // 5) wout cast (into dead pre region)
  cast_k<<<2048, 256, 0, stream>>>(wout, o_wout, (DM * DI) / 4);

  // 6) output = (h_seq * gate) @ out_proj_w^T  — multiply fused into A-staging
  gemm_k<<<dim3(DM / 128, ROWS / 128), 256, 0, stream>>>(
      o_hseq, o_gate, o_wout, ROWS, DM, DI, 3, nullptr, out, nullptr);
}